// Round 8
// baseline (245.669 us; speedup 1.0000x reference)
//
#include <hip/hip_runtime.h>
#include <hip/hip_bf16.h>

// Problem constants: M=100000 points, K=27 offsets, Cin=Cout=64.
#define NPTS 100000
#define KOFF 27
#define KPAD 28          // padded K: tile 27 = zero weights + zero-row gathers
#define NCH  64

typedef __attribute__((ext_vector_type(8))) short bf16x8;   // 8 bf16 in 4 VGPRs
typedef __attribute__((ext_vector_type(8))) unsigned short u16x8;
typedef __attribute__((ext_vector_type(4))) float f32x4;
typedef __attribute__((ext_vector_type(4))) unsigned int u32x4;

static __device__ __forceinline__ unsigned short f2bf(float x) {
  union { float f; unsigned int u; } v; v.f = x;
  unsigned int r = v.u + 0x7fffu + ((v.u >> 16) & 1u);   // RTNE
  return (unsigned short)(r >> 16);
}

// feats fp32 (M x 64) -> bf16 (M+1 x 64); row NPTS is all-zero.
__global__ void convert_feats_kernel(const float* __restrict__ feats,
                                     unsigned short* __restrict__ fb) {
  size_t tid  = (size_t)blockIdx.x * blockDim.x + threadIdx.x;
  size_t base = tid * 8;
  const size_t valid_total = (size_t)NPTS * NCH;
  const size_t total       = valid_total + NCH;
  if (base >= total) return;
  u16x8 r;
  if (base < valid_total) {
    const float4 a = *reinterpret_cast<const float4*>(feats + base);
    const float4 b = *reinterpret_cast<const float4*>(feats + base + 4);
    r[0] = f2bf(a.x); r[1] = f2bf(a.y); r[2] = f2bf(a.z); r[3] = f2bf(a.w);
    r[4] = f2bf(b.x); r[5] = f2bf(b.y); r[6] = f2bf(b.z); r[7] = f2bf(b.w);
  } else {
    #pragma unroll
    for (int j = 0; j < 8; ++j) r[j] = 0;
  }
  *reinterpret_cast<u16x8*>(fb + base) = r;
}

// weight fp32 [k][cin][cout] -> bf16 lane-major fragment layout (1KB blocks).
__global__ void convert_weight_kernel(const float* __restrict__ w,
                                      unsigned short* __restrict__ wt) {
  int tid = blockIdx.x * 256 + threadIdx.x;
  if (tid >= KPAD * NCH * NCH) return;
  int ko  = tid >> 12;
  int rem = tid & 4095;
  int c   = rem >> 6;
  int o   = rem & 63;
  unsigned short val = 0;
  if (ko < KOFF) val = f2bf(w[(size_t)ko * 4096 + c * 64 + o]);
  int dst = (ko * 8 + (o >> 4) * 2 + (c >> 5)) * 512
          + (((c >> 3) & 3) * 16 + (o & 15)) * 8 + (c & 7);
  wt[dst] = val;
}

// ===================== FULL KERNEL (unchanged from R7) ======================
__global__ __launch_bounds__(256, 4)
void spconv_kernel(const unsigned short* __restrict__ fb,
                   const int* __restrict__ rulebook,
                   const unsigned short* __restrict__ wl,
                   const float* __restrict__ feats,
                   const float* __restrict__ bias,
                   float* __restrict__ out) {
  __shared__ int s_off[128][KPAD];
  __shared__ int s_cnt[128];

  const int tid = threadIdx.x;
  const int m0  = blockIdx.x * 128;

  if (tid < 128) s_cnt[tid] = 0;
  __syncthreads();

  for (int f = tid; f < 128 * KPAD; f += 256) {
    int r = f / KPAD, k = f - r * KPAD;
    int m = m0 + r;
    int off = NPTS * 128;
    if (m < NPTS && k < KOFF) {
      int v = rulebook[(size_t)m * KOFF + k];
      if (v >= 0) { off = v * 128; atomicAdd(&s_cnt[r], 1); }
    }
    s_off[r][k] = off;
  }
  __syncthreads();

  const int wave = tid >> 6;
  const int lane = tid & 63;
  const int lr   = lane & 15;
  const int lk   = lane >> 4;
  const int coff_b = lk * 16;
  const int row0 = wave * 32 + lr;
  const int row1 = wave * 32 + 16 + lr;

  const char* fbase = (const char*)fb;
  const unsigned short* wlane = wl + lane * 8;

  f32x4 acc0[4] = {f32x4{0,0,0,0}, f32x4{0,0,0,0}, f32x4{0,0,0,0}, f32x4{0,0,0,0}};
  f32x4 acc1[4] = {f32x4{0,0,0,0}, f32x4{0,0,0,0}, f32x4{0,0,0,0}, f32x4{0,0,0,0}};

  bf16x8 A0t0h0, A0t0h1, A0t1h0, A0t1h1;
  bf16x8 A1t0h0, A1t0h1, A1t1h0, A1t1h1;
  bf16x8 B0, B1, B2, B3, B4, B5, B6, B7;
  int oa0, oa1, ob0, ob1;

#define LOADA(T0H0, T0H1, T1H0, T1H1, O0, O1) {                               \
    const char* p0_ = fbase + (size_t)(unsigned)(O0);                         \
    const char* p1_ = fbase + (size_t)(unsigned)(O1);                         \
    T0H0 = *reinterpret_cast<const bf16x8*>(p0_ + coff_b);                    \
    T0H1 = *reinterpret_cast<const bf16x8*>(p0_ + 64 + coff_b);               \
    T1H0 = *reinterpret_cast<const bf16x8*>(p1_ + coff_b);                    \
    T1H1 = *reinterpret_cast<const bf16x8*>(p1_ + 64 + coff_b);               \
  }

#define LOADB(KO) {                                                           \
    const unsigned short* wb_ = wlane + (size_t)(KO) * 4096;                  \
    B0 = *reinterpret_cast<const bf16x8*>(wb_ + 0 * 512);                     \
    B1 = *reinterpret_cast<const bf16x8*>(wb_ + 1 * 512);                     \
    B2 = *reinterpret_cast<const bf16x8*>(wb_ + 2 * 512);                     \
    B3 = *reinterpret_cast<const bf16x8*>(wb_ + 3 * 512);                     \
    B4 = *reinterpret_cast<const bf16x8*>(wb_ + 4 * 512);                     \
    B5 = *reinterpret_cast<const bf16x8*>(wb_ + 5 * 512);                     \
    B6 = *reinterpret_cast<const bf16x8*>(wb_ + 6 * 512);                     \
    B7 = *reinterpret_cast<const bf16x8*>(wb_ + 7 * 512);                     \
  }

#define MFMA_STEP(T0H0, T0H1, T1H0, T1H1) {                                   \
    acc0[0] = __builtin_amdgcn_mfma_f32_16x16x32_bf16(T0H0, B0, acc0[0],0,0,0);\
    acc0[0] = __builtin_amdgcn_mfma_f32_16x16x32_bf16(T0H1, B1, acc0[0],0,0,0);\
    acc1[0] = __builtin_amdgcn_mfma_f32_16x16x32_bf16(T1H0, B0, acc1[0],0,0,0);\
    acc1[0] = __builtin_amdgcn_mfma_f32_16x16x32_bf16(T1H1, B1, acc1[0],0,0,0);\
    acc0[1] = __builtin_amdgcn_mfma_f32_16x16x32_bf16(T0H0, B2, acc0[1],0,0,0);\
    acc0[1] = __builtin_amdgcn_mfma_f32_16x16x32_bf16(T0H1, B3, acc0[1],0,0,0);\
    acc1[1] = __builtin_amdgcn_mfma_f32_16x16x32_bf16(T1H0, B2, acc1[1],0,0,0);\
    acc1[1] = __builtin_amdgcn_mfma_f32_16x16x32_bf16(T1H1, B3, acc1[1],0,0,0);\
    acc0[2] = __builtin_amdgcn_mfma_f32_16x16x32_bf16(T0H0, B4, acc0[2],0,0,0);\
    acc0[2] = __builtin_amdgcn_mfma_f32_16x16x32_bf16(T0H1, B5, acc0[2],0,0,0);\
    acc1[2] = __builtin_amdgcn_mfma_f32_16x16x32_bf16(T1H0, B4, acc1[2],0,0,0);\
    acc1[2] = __builtin_amdgcn_mfma_f32_16x16x32_bf16(T1H1, B5, acc1[2],0,0,0);\
    acc0[3] = __builtin_amdgcn_mfma_f32_16x16x32_bf16(T0H0, B6, acc0[3],0,0,0);\
    acc0[3] = __builtin_amdgcn_mfma_f32_16x16x32_bf16(T0H1, B7, acc0[3],0,0,0);\
    acc1[3] = __builtin_amdgcn_mfma_f32_16x16x32_bf16(T1H0, B6, acc1[3],0,0,0);\
    acc1[3] = __builtin_amdgcn_mfma_f32_16x16x32_bf16(T1H1, B7, acc1[3],0,0,0);\
  }

  oa0 = s_off[row0][0]; oa1 = s_off[row1][0];
  ob0 = s_off[row0][1]; ob1 = s_off[row1][1];
  LOADA(A0t0h0, A0t0h1, A0t1h0, A0t1h1, oa0, oa1)
  LOADA(A1t0h0, A1t0h1, A1t1h0, A1t1h1, ob0, ob1)
  LOADB(0)
  oa0 = s_off[row0][2]; oa1 = s_off[row1][2];
  ob0 = s_off[row0][3]; ob1 = s_off[row1][3];

  #pragma unroll 1
  for (int kk = 0; kk < KPAD / 2; ++kk) {
    const int ko = kk * 2;
    MFMA_STEP(A0t0h0, A0t0h1, A0t1h0, A0t1h1)
    LOADB(ko + 1)
    if (ko + 2 < KPAD) {
      LOADA(A0t0h0, A0t0h1, A0t1h0, A0t1h1, oa0, oa1)
    }
    if (ko + 4 < KPAD) {
      oa0 = s_off[row0][ko + 4]; oa1 = s_off[row1][ko + 4];
    }
    MFMA_STEP(A1t0h0, A1t0h1, A1t1h0, A1t1h1)
    if (ko + 2 < KPAD) LOADB(ko + 2)
    if (ko + 3 < KPAD) {
      LOADA(A1t0h0, A1t0h1, A1t1h0, A1t1h1, ob0, ob1)
    }
    if (ko + 5 < KPAD) {
      ob0 = s_off[row0][ko + 5]; ob1 = s_off[row1][ko + 5];
    }
  }
#undef LOADA
#undef LOADB
#undef MFMA_STEP

  #pragma unroll
  for (int rt = 0; rt < 2; ++rt) {
    #pragma unroll
    for (int nt = 0; nt < 4; ++nt) {
      const int col = nt * 16 + lr;
      const float b = bias[col];
      #pragma unroll
      for (int i = 0; i < 4; ++i) {
        const int rl = wave * 32 + rt * 16 + lk * 4 + i;
        const int m  = m0 + rl;
        if (m < NPTS) {
          const float denom = (float)max(s_cnt[rl], 1);
          const float a = (rt == 0) ? acc0[nt][i] : acc1[nt][i];
          out[(size_t)m * NCH + col] =
              a / denom + b + feats[(size_t)m * NCH + col];
        }
      }
    }
  }
}

// ===================== ABLATION PROBES (write only to d_ws) =================
// Probe 1: the full A-gather stream, same tiling/offsets as spconv, XOR-
// combined (cheap consumers -> compiler can pipeline deeply). Measures the
// gather stream's best-case throughput G.
__global__ __launch_bounds__(256)
void abl_gather_kernel(const unsigned short* __restrict__ fb,
                       const int* __restrict__ rulebook,
                       unsigned int* __restrict__ sink) {
  __shared__ int s_off[128][KPAD];
  const int tid = threadIdx.x;
  const int m0  = blockIdx.x * 128;

  for (int f = tid; f < 128 * KPAD; f += 256) {
    int r = f / KPAD, k = f - r * KPAD;
    int m = m0 + r;
    int off = NPTS * 128;
    if (m < NPTS && k < KOFF) {
      int v = rulebook[(size_t)m * KOFF + k];
      if (v >= 0) off = v * 128;
    }
    s_off[r][k] = off;
  }
  __syncthreads();

  const int wave = tid >> 6;
  const int lane = tid & 63;
  const int lr   = lane & 15;
  const int lk   = lane >> 4;
  const int coff_b = lk * 16;
  const int row0 = wave * 32 + lr;
  const int row1 = wave * 32 + 16 + lr;
  const char* fbase = (const char*)fb;

  u32x4 x0{0,0,0,0}, x1{0,0,0,0}, x2{0,0,0,0}, x3{0,0,0,0};
  #pragma unroll 4
  for (int ko = 0; ko < KPAD; ++ko) {
    const char* p0 = fbase + (size_t)(unsigned)s_off[row0][ko];
    const char* p1 = fbase + (size_t)(unsigned)s_off[row1][ko];
    x0 ^= *reinterpret_cast<const u32x4*>(p0 + coff_b);
    x1 ^= *reinterpret_cast<const u32x4*>(p0 + 64 + coff_b);
    x2 ^= *reinterpret_cast<const u32x4*>(p1 + coff_b);
    x3 ^= *reinterpret_cast<const u32x4*>(p1 + 64 + coff_b);
  }
  u32x4 x = (x0 ^ x1) ^ (x2 ^ x3);
  *reinterpret_cast<u32x4*>(sink + ((size_t)blockIdx.x * 256 + tid) * 4) = x;
}

// Probe 2: B-loads + full MFMA chain, constant A (no gathers). Measures B+compute
// cost in the consume-immediately shape of the full kernel.
__global__ __launch_bounds__(256)
void abl_bmfma_kernel(const unsigned short* __restrict__ wl,
                      float* __restrict__ sink) {
  const int tid  = threadIdx.x;
  const int lane = tid & 63;
  const unsigned short* wlane = wl + lane * 8;

  f32x4 acc0[4] = {f32x4{0,0,0,0}, f32x4{0,0,0,0}, f32x4{0,0,0,0}, f32x4{0,0,0,0}};
  f32x4 acc1[4] = {f32x4{0,0,0,0}, f32x4{0,0,0,0}, f32x4{0,0,0,0}, f32x4{0,0,0,0}};

  bf16x8 A;
  #pragma unroll
  for (int j = 0; j < 8; ++j) A[j] = (short)(lane * 8 + j + 1);

  bf16x8 B0, B1, B2, B3, B4, B5, B6, B7;

  #pragma unroll 1
  for (int ko = 0; ko < KPAD; ++ko) {
    const unsigned short* wb_ = wlane + (size_t)ko * 4096;
    B0 = *reinterpret_cast<const bf16x8*>(wb_ + 0 * 512);
    B1 = *reinterpret_cast<const bf16x8*>(wb_ + 1 * 512);
    B2 = *reinterpret_cast<const bf16x8*>(wb_ + 2 * 512);
    B3 = *reinterpret_cast<const bf16x8*>(wb_ + 3 * 512);
    B4 = *reinterpret_cast<const bf16x8*>(wb_ + 4 * 512);
    B5 = *reinterpret_cast<const bf16x8*>(wb_ + 5 * 512);
    B6 = *reinterpret_cast<const bf16x8*>(wb_ + 6 * 512);
    B7 = *reinterpret_cast<const bf16x8*>(wb_ + 7 * 512);
    acc0[0] = __builtin_amdgcn_mfma_f32_16x16x32_bf16(A, B0, acc0[0],0,0,0);
    acc0[0] = __builtin_amdgcn_mfma_f32_16x16x32_bf16(A, B1, acc0[0],0,0,0);
    acc1[0] = __builtin_amdgcn_mfma_f32_16x16x32_bf16(A, B0, acc1[0],0,0,0);
    acc1[0] = __builtin_amdgcn_mfma_f32_16x16x32_bf16(A, B1, acc1[0],0,0,0);
    acc0[1] = __builtin_amdgcn_mfma_f32_16x16x32_bf16(A, B2, acc0[1],0,0,0);
    acc0[1] = __builtin_amdgcn_mfma_f32_16x16x32_bf16(A, B3, acc0[1],0,0,0);
    acc1[1] = __builtin_amdgcn_mfma_f32_16x16x32_bf16(A, B2, acc1[1],0,0,0);
    acc1[1] = __builtin_amdgcn_mfma_f32_16x16x32_bf16(A, B3, acc1[1],0,0,0);
    acc0[2] = __builtin_amdgcn_mfma_f32_16x16x32_bf16(A, B4, acc0[2],0,0,0);
    acc0[2] = __builtin_amdgcn_mfma_f32_16x16x32_bf16(A, B5, acc0[2],0,0,0);
    acc1[2] = __builtin_amdgcn_mfma_f32_16x16x32_bf16(A, B4, acc1[2],0,0,0);
    acc1[2] = __builtin_amdgcn_mfma_f32_16x16x32_bf16(A, B5, acc1[2],0,0,0);
    acc0[3] = __builtin_amdgcn_mfma_f32_16x16x32_bf16(A, B6, acc0[3],0,0,0);
    acc0[3] = __builtin_amdgcn_mfma_f32_16x16x32_bf16(A, B7, acc0[3],0,0,0);
    acc1[3] = __builtin_amdgcn_mfma_f32_16x16x32_bf16(A, B6, acc1[3],0,0,0);
    acc1[3] = __builtin_amdgcn_mfma_f32_16x16x32_bf16(A, B7, acc1[3],0,0,0);
  }

  f32x4 r = acc0[0];
  r += acc0[1]; r += acc0[2]; r += acc0[3];
  r += acc1[0]; r += acc1[1]; r += acc1[2]; r += acc1[3];
  *reinterpret_cast<f32x4*>(sink + ((size_t)blockIdx.x * 256 + tid) * 4) = r;
}

extern "C" void kernel_launch(void* const* d_in, const int* in_sizes, int n_in,
                              void* d_out, int out_size, void* d_ws, size_t ws_size,
                              hipStream_t stream) {
  const float* feats    = (const float*)d_in[0];
  const int*   rulebook = (const int*)d_in[1];
  const float* weight   = (const float*)d_in[2];
  const float* bias     = (const float*)d_in[3];
  float* out = (float*)d_out;

  unsigned short* fb = (unsigned short*)d_ws;
  const size_t fb_bytes = (size_t)(NPTS + 1) * NCH * sizeof(unsigned short);
  const size_t wt_off   = (fb_bytes + 255) & ~(size_t)255;
  unsigned short* wl = (unsigned short*)((char*)d_ws + wt_off);

  {
    const size_t total = (size_t)(NPTS + 1) * NCH;
    const int threads = (int)((total + 7) / 8);
    convert_feats_kernel<<<(threads + 255) / 256, 256, 0, stream>>>(feats, fb);
  }
  {
    const int n = KPAD * NCH * NCH;
    convert_weight_kernel<<<(n + 255) / 256, 256, 0, stream>>>(weight, wl);
  }
  const int nblk = (NPTS + 127) / 128;   // 782
  spconv_kernel<<<nblk, 256, 0, stream>>>(fb, rulebook, wl, feats, bias, out);

  // --- ablation probes: sink into ws (fb region; converts rewrite it each
  // replay, and probes run AFTER spconv so d_out is unaffected). Probe reads
  // use only addresses (rulebook/wl), which they never clobber.
  abl_gather_kernel<<<nblk, 256, 0, stream>>>(fb, rulebook, (unsigned int*)d_ws);
  abl_gather_kernel<<<nblk, 256, 0, stream>>>(fb, rulebook, (unsigned int*)d_ws);
  abl_bmfma_kernel<<<nblk, 256, 0, stream>>>(wl, (float*)d_ws);
}

// Round 9
// 90.966 us; speedup vs baseline: 2.7007x; 2.7007x over previous
//
#include <hip/hip_runtime.h>
#include <hip/hip_bf16.h>

// Problem constants: M=100000 points, K=27 offsets, Cin=Cout=64.
// R9: fp8 (OCP e4m3) feats + weights. Gather row = 64B (was 128B) -> halves
// fabric line traffic and doubles per-XCD L2 residency of the gather table.
#define NPTS 100000
#define KOFF 27
#define KPAD 28          // padded K: tile 27 = zero weights + zero-row gathers
#define NCH  64

typedef __attribute__((ext_vector_type(4))) float f32x4;
typedef __attribute__((ext_vector_type(4))) unsigned int u32x4;

// feats fp32 (M x 64) -> fp8 e4m3 (M+1 x 64); row NPTS all-zero (gather target
// for invalid rulebook entries). 16 elems/thread, 16B stores. HW cvt (RNE, OCP
// on gfx950) guarantees format match with the fp8 MFMA.
__global__ void convert_feats_kernel(const float* __restrict__ feats,
                                     unsigned char* __restrict__ f8) {
  size_t tid  = (size_t)blockIdx.x * blockDim.x + threadIdx.x;
  size_t base = tid * 16;
  const size_t valid = (size_t)NPTS * NCH;      // 6,400,000 (divisible by 16)
  const size_t total = valid + NCH;             // + zero row
  if (base >= total) return;
  unsigned int w0 = 0, w1 = 0, w2 = 0, w3 = 0;
  if (base < valid) {
    const float4 a = *reinterpret_cast<const float4*>(feats + base);
    const float4 b = *reinterpret_cast<const float4*>(feats + base + 4);
    const float4 c = *reinterpret_cast<const float4*>(feats + base + 8);
    const float4 d = *reinterpret_cast<const float4*>(feats + base + 12);
    int p;
    p = __builtin_amdgcn_cvt_pk_fp8_f32(a.x, a.y, 0, false);
    p = __builtin_amdgcn_cvt_pk_fp8_f32(a.z, a.w, p, true);  w0 = (unsigned)p;
    p = __builtin_amdgcn_cvt_pk_fp8_f32(b.x, b.y, 0, false);
    p = __builtin_amdgcn_cvt_pk_fp8_f32(b.z, b.w, p, true);  w1 = (unsigned)p;
    p = __builtin_amdgcn_cvt_pk_fp8_f32(c.x, c.y, 0, false);
    p = __builtin_amdgcn_cvt_pk_fp8_f32(c.z, c.w, p, true);  w2 = (unsigned)p;
    p = __builtin_amdgcn_cvt_pk_fp8_f32(d.x, d.y, 0, false);
    p = __builtin_amdgcn_cvt_pk_fp8_f32(d.z, d.w, p, true);  w3 = (unsigned)p;
  }
  *reinterpret_cast<u32x4*>(f8 + base) = u32x4{w0, w1, w2, w3};
}

// weight fp32 [k][cin][cout] -> fp8 e4m3 lane-major fragment layout:
// fragment (ko, nt=o>>4, chunk=c>>5) is a contiguous 512B block; lane L's 8
// bytes at L*8; within-lane byte j = c&7; lane = ((c>>3)&3)*16 + (o&15).
// MFMA 16x16x32 fragment mapping: k = 8*(lane>>4)+j, n (or A-row i) = lane&15.
__global__ void convert_weight_kernel(const float* __restrict__ w,
                                      unsigned char* __restrict__ wt) {
  int tid = blockIdx.x * 256 + threadIdx.x;
  if (tid >= KPAD * NCH * NCH) return;
  int ko  = tid >> 12;
  int rem = tid & 4095;
  int c   = rem >> 6;
  int o   = rem & 63;
  float val = (ko < KOFF) ? w[(size_t)ko * 4096 + c * 64 + o] : 0.0f;
  int p = __builtin_amdgcn_cvt_pk_fp8_f32(val, 0.0f, 0, false);
  int dst = (ko * 8 + (o >> 4) * 2 + (c >> 5)) * 512
          + (((c >> 3) & 3) * 16 + (o & 15)) * 8 + (c & 7);
  wt[dst] = (unsigned char)(p & 0xff);
}

// Main kernel: block = 128 rows, 4 waves; wave owns 32 rows (2 row-tiles of
// 16) x 64 cout x all 28 kos. R7 schedule (vmcnt-retire-order-aware: MFMA(ko)
// drains only through its young B-batch; A-gathers always older, latency
// pipelined), with fp8 operands: A row = 64B (2x 8B loads per row), B
// fragment = 512B block (8B/lane).
__global__ __launch_bounds__(256, 4)
void spconv_kernel(const unsigned char* __restrict__ f8,       // (NPTS+1) x 64 fp8
                   const int* __restrict__ rulebook,           // NPTS x 27 int32
                   const unsigned char* __restrict__ wl,       // lane-major fp8 weights
                   const float* __restrict__ feats,            // NPTS x 64 fp32 (residual)
                   const float* __restrict__ bias,             // 64 fp32
                   float* __restrict__ out) {                  // NPTS x 64 fp32
  __shared__ int s_off[128][KPAD];   // BYTE offsets into f8 (idx*64)
  __shared__ int s_cnt[128];

  const int tid = threadIdx.x;
  const int m0  = blockIdx.x * 128;

  if (tid < 128) s_cnt[tid] = 0;
  __syncthreads();

  for (int f = tid; f < 128 * KPAD; f += 256) {
    int r = f / KPAD, k = f - r * KPAD;
    int m = m0 + r;
    int off = NPTS * 64;
    if (m < NPTS && k < KOFF) {
      int v = rulebook[(size_t)m * KOFF + k];
      if (v >= 0) { off = v * 64; atomicAdd(&s_cnt[r], 1); }
    }
    s_off[r][k] = off;
  }
  __syncthreads();

  const int wave = tid >> 6;
  const int lane = tid & 63;
  const int lr   = lane & 15;
  const int lk   = lane >> 4;
  const int lk8  = lk * 8;             // byte offset within a 32B chunk
  const int row0 = wave * 32 + lr;
  const int row1 = wave * 32 + 16 + lr;

  const char* fbase = (const char*)f8;
  const char* wlane = (const char*)wl + lane * 8;

  f32x4 acc0[4] = {f32x4{0,0,0,0}, f32x4{0,0,0,0}, f32x4{0,0,0,0}, f32x4{0,0,0,0}};
  f32x4 acc1[4] = {f32x4{0,0,0,0}, f32x4{0,0,0,0}, f32x4{0,0,0,0}, f32x4{0,0,0,0}};

  // A pipeline: 2 sets (distance 2 over ko); t = row-tile, c = cin-chunk.
  long A0t0c0, A0t0c1, A0t1c0, A0t1c1;
  long A1t0c0, A1t0c1, A1t1c0, A1t1c1;
  // B: single set, reloaded each ko after consumption.
  long B0, B1, B2, B3, B4, B5, B6, B7;
  int oa0, oa1, ob0, ob1;

#define LOADA(T0C0, T0C1, T1C0, T1C1, O0, O1) {                               \
    const char* p0_ = fbase + (size_t)(unsigned)(O0);                         \
    const char* p1_ = fbase + (size_t)(unsigned)(O1);                         \
    T0C0 = *reinterpret_cast<const long*>(p0_ + lk8);                         \
    T0C1 = *reinterpret_cast<const long*>(p0_ + 32 + lk8);                    \
    T1C0 = *reinterpret_cast<const long*>(p1_ + lk8);                         \
    T1C1 = *reinterpret_cast<const long*>(p1_ + 32 + lk8);                    \
  }

#define LOADB(KO) {                                                           \
    const char* wb_ = wlane + (size_t)(KO) * 4096;                            \
    B0 = *reinterpret_cast<const long*>(wb_ + 0 * 512);                       \
    B1 = *reinterpret_cast<const long*>(wb_ + 1 * 512);                       \
    B2 = *reinterpret_cast<const long*>(wb_ + 2 * 512);                       \
    B3 = *reinterpret_cast<const long*>(wb_ + 3 * 512);                       \
    B4 = *reinterpret_cast<const long*>(wb_ + 4 * 512);                       \
    B5 = *reinterpret_cast<const long*>(wb_ + 5 * 512);                       \
    B6 = *reinterpret_cast<const long*>(wb_ + 6 * 512);                       \
    B7 = *reinterpret_cast<const long*>(wb_ + 7 * 512);                       \
  }

#define MFMA_STEP(T0C0, T0C1, T1C0, T1C1) {                                   \
    acc0[0] = __builtin_amdgcn_mfma_f32_16x16x32_fp8_fp8(T0C0, B0, acc0[0],0,0,0);\
    acc0[0] = __builtin_amdgcn_mfma_f32_16x16x32_fp8_fp8(T0C1, B1, acc0[0],0,0,0);\
    acc1[0] = __builtin_amdgcn_mfma_f32_16x16x32_fp8_fp8(T1C0, B0, acc1[0],0,0,0);\
    acc1[0] = __builtin_amdgcn_mfma_f32_16x16x32_fp8_fp8(T1C1, B1, acc1[0],0,0,0);\
    acc0[1] = __builtin_amdgcn_mfma_f32_16x16x32_fp8_fp8(T0C0, B2, acc0[1],0,0,0);\
    acc0[1] = __builtin_amdgcn_mfma_f32_16x16x32_fp8_fp8(T0C1, B3, acc0[1],0,0,0);\
    acc1[1] = __builtin_amdgcn_mfma_f32_16x16x32_fp8_fp8(T1C0, B2, acc1[1],0,0,0);\
    acc1[1] = __builtin_amdgcn_mfma_f32_16x16x32_fp8_fp8(T1C1, B3, acc1[1],0,0,0);\
    acc0[2] = __builtin_amdgcn_mfma_f32_16x16x32_fp8_fp8(T0C0, B4, acc0[2],0,0,0);\
    acc0[2] = __builtin_amdgcn_mfma_f32_16x16x32_fp8_fp8(T0C1, B5, acc0[2],0,0,0);\
    acc1[2] = __builtin_amdgcn_mfma_f32_16x16x32_fp8_fp8(T1C0, B4, acc1[2],0,0,0);\
    acc1[2] = __builtin_amdgcn_mfma_f32_16x16x32_fp8_fp8(T1C1, B5, acc1[2],0,0,0);\
    acc0[3] = __builtin_amdgcn_mfma_f32_16x16x32_fp8_fp8(T0C0, B6, acc0[3],0,0,0);\
    acc0[3] = __builtin_amdgcn_mfma_f32_16x16x32_fp8_fp8(T0C1, B7, acc0[3],0,0,0);\
    acc1[3] = __builtin_amdgcn_mfma_f32_16x16x32_fp8_fp8(T1C0, B6, acc1[3],0,0,0);\
    acc1[3] = __builtin_amdgcn_mfma_f32_16x16x32_fp8_fp8(T1C1, B7, acc1[3],0,0,0);\
  }

  // Prologue: A(0), A(1) in flight; B(0) in flight; offsets for ko 2,3 cached.
  oa0 = s_off[row0][0]; oa1 = s_off[row1][0];
  ob0 = s_off[row0][1]; ob1 = s_off[row1][1];
  LOADA(A0t0c0, A0t0c1, A0t1c0, A0t1c1, oa0, oa1)
  LOADA(A1t0c0, A1t0c1, A1t1c0, A1t1c1, ob0, ob1)
  LOADB(0)
  oa0 = s_off[row0][2]; oa1 = s_off[row1][2];
  ob0 = s_off[row0][3]; ob1 = s_off[row1][3];

  #pragma unroll 1
  for (int kk = 0; kk < KPAD / 2; ++kk) {
    const int ko = kk * 2;
    // ---- even ko ----
    MFMA_STEP(A0t0c0, A0t0c1, A0t1c0, A0t1c1)          // consumes A(ko), B(ko)
    LOADB(ko + 1)                                      // refill B (single set)
    if (ko + 2 < KPAD) {
      LOADA(A0t0c0, A0t0c1, A0t1c0, A0t1c1, oa0, oa1)  // A(ko+2)
    }
    if (ko + 4 < KPAD) {
      oa0 = s_off[row0][ko + 4]; oa1 = s_off[row1][ko + 4];
    }
    // ---- odd ko ----
    MFMA_STEP(A1t0c0, A1t0c1, A1t1c0, A1t1c1)          // consumes A(ko+1), B(ko+1)
    if (ko + 2 < KPAD) LOADB(ko + 2)
    if (ko + 3 < KPAD) {
      LOADA(A1t0c0, A1t0c1, A1t1c0, A1t1c1, ob0, ob1)  // A(ko+3)
    }
    if (ko + 5 < KPAD) {
      ob0 = s_off[row0][ko + 5]; ob1 = s_off[row1][ko + 5];
    }
  }
#undef LOADA
#undef LOADB
#undef MFMA_STEP

  // Epilogue: /denom + bias + residual (fp32 path unchanged).
  #pragma unroll
  for (int rt = 0; rt < 2; ++rt) {
    #pragma unroll
    for (int nt = 0; nt < 4; ++nt) {
      const int col = nt * 16 + lr;
      const float b = bias[col];
      #pragma unroll
      for (int i = 0; i < 4; ++i) {
        const int rl = wave * 32 + rt * 16 + lk * 4 + i;
        const int m  = m0 + rl;
        if (m < NPTS) {
          const float denom = (float)max(s_cnt[rl], 1);
          const float a = (rt == 0) ? acc0[nt][i] : acc1[nt][i];
          out[(size_t)m * NCH + col] =
              a / denom + b + feats[(size_t)m * NCH + col];
        }
      }
    }
  }
}

extern "C" void kernel_launch(void* const* d_in, const int* in_sizes, int n_in,
                              void* d_out, int out_size, void* d_ws, size_t ws_size,
                              hipStream_t stream) {
  const float* feats    = (const float*)d_in[0];
  const int*   rulebook = (const int*)d_in[1];
  const float* weight   = (const float*)d_in[2];
  const float* bias     = (const float*)d_in[3];
  float* out = (float*)d_out;

  // Workspace: [0, ~6.4MB) feats fp8 (M+1 rows x 64B); then weights fp8 (112KB).
  unsigned char* f8 = (unsigned char*)d_ws;
  const size_t f8_bytes = (size_t)(NPTS + 1) * NCH;          // 6,400,064
  const size_t wt_off   = (f8_bytes + 511) & ~(size_t)511;
  unsigned char* wl = (unsigned char*)((char*)d_ws + wt_off);

  {
    const size_t total = (size_t)(NPTS + 1) * NCH;           // fp8 bytes
    const int threads = (int)((total + 15) / 16);
    convert_feats_kernel<<<(threads + 255) / 256, 256, 0, stream>>>(feats, f8);
  }
  {
    const int n = KPAD * NCH * NCH;
    convert_weight_kernel<<<(n + 255) / 256, 256, 0, stream>>>(weight, wl);
  }
  {
    const int nblk = (NPTS + 127) / 128;   // 782
    spconv_kernel<<<nblk, 256, 0, stream>>>(f8, rulebook, wl, feats, bias, out);
  }
}